// Round 1
// baseline (7113.386 us; speedup 1.0000x reference)
//
#include <hip/hip_runtime.h>
#include <hip/hip_bf16.h>
#include <stdint.h>

// ---------------------------------------------------------------------------
// GraphDecoder forward, MI355X.
// Structure:
//   prep        : bf16 hi/lo weight + zc conversions into ws
//   gemm_split  : generic chunk-mapped bf16-split MFMA GEMM (3 uses)
//   gru_seq     : 50-step GRU, h in LDS, heads fused (1 launch, 256 blocks)
//   edge_bcast  : row dot + 2450-wide broadcast
// Precision: split bf16 (hi+lo) on every accuracy-critical GEMM; fp32
// gate math; plain-bf16 only where error analysis says it is safe.
// ---------------------------------------------------------------------------

typedef unsigned short u16;
typedef __attribute__((ext_vector_type(8))) short bf16x8;
typedef __attribute__((ext_vector_type(4))) float f32x4;

#define MFMA16(A, B, C) __builtin_amdgcn_mfma_f32_16x16x32_bf16((A), (B), (C), 0, 0, 0)

#define BATCH 16384
#define R1OFF 802816      // type_logits  [B,50,15]
#define R2OFF 13090816    // param_preds  [B,50,14]
#define R3OFF 24559616    // edge_logits  [B,2450]

__device__ __forceinline__ u16 f2b(float x) {
  union { float f; unsigned u; } v; v.f = x;
  unsigned r = v.u + 0x7fffu + ((v.u >> 16) & 1u);
  return (u16)(r >> 16);
}
__device__ __forceinline__ float b2f(u16 h) {
  union { unsigned u; float f; } v; v.u = ((unsigned)h) << 16; return v.f;
}
__device__ __forceinline__ float sigm(float x) {
  return __builtin_amdgcn_rcpf(1.f + __expf(-x));
}
__device__ __forceinline__ float tanhfast(float x) {
  // 1 - 2/(1+e^{2x}) : NaN-free at +-inf
  return 1.f - 2.f * __builtin_amdgcn_rcpf(1.f + __expf(2.f * x));
}
__device__ __forceinline__ void gload_lds16(const u16* g, u16* l) {
  __builtin_amdgcn_global_load_lds(
      (const __attribute__((address_space(1))) unsigned int*)g,
      (__attribute__((address_space(3))) unsigned int*)l, 16, 0, 0);
}

// ---------------------------------------------------------------------------
// prep: build all bf16 (hi/lo) staging buffers in ws.
//  Azc  [16384][576] : cols 0:260 zc_hi, 288:548 zc_lo, rest 0
//  B1t  [1280][576]  : W^T of [Wn1|Wi|Wih_top], hi at 0:260, lo at 288:548
//  Wgru [768][544]   : k 0:256 Whh_hi^T, 256:512 Whh_lo^T, 512:541 Wih_bot^T
//  Whead[32][256]    : n 0:15 Wt^T, 16:30 Wp^T (hi only)
//  Wedge[256][800]   : We1^T (hi only), k 772:800 zero
//  Wn2t [64][256]    : Wn2^T (hi only), rows 49:64 zero
// ---------------------------------------------------------------------------
__global__ __launch_bounds__(256) void prep(
    const float* __restrict__ z, const float* __restrict__ cond,
    const float* __restrict__ Wn1, const float* __restrict__ Wi,
    const float* __restrict__ Wih, const float* __restrict__ Whh,
    const float* __restrict__ Wt, const float* __restrict__ Wp,
    const float* __restrict__ We1, const float* __restrict__ Wn2,
    u16* __restrict__ Azc, u16* __restrict__ B1t, u16* __restrict__ Wgru,
    u16* __restrict__ Whead, u16* __restrict__ Wedge, u16* __restrict__ Wn2t) {
  int i = blockIdx.x * 256 + threadIdx.x;
  if (i < 9437184) {  // Azc
    int b = i / 576, k = i - b * 576;
    int kk = (k < 260) ? k : ((k >= 288 && k < 548) ? k - 288 : -1);
    u16 o = 0;
    if (kk >= 0) {
      float x = (kk < 256) ? z[b * 256 + kk] : cond[b * 4 + (kk - 256)];
      o = (k < 260) ? f2b(x) : f2b(x - b2f(f2b(x)));
    }
    Azc[i] = o;
    return;
  }
  i -= 9437184;
  if (i < 737280) {  // B1t
    int n = i / 576, k = i - n * 576;
    int kk = (k < 260) ? k : ((k >= 288 && k < 548) ? k - 288 : -1);
    u16 o = 0;
    if (kk >= 0) {
      float x = (n < 256) ? Wn1[kk * 256 + n]
                          : (n < 512 ? Wi[kk * 256 + (n - 256)]
                                     : Wih[kk * 768 + (n - 512)]);
      o = (k < 260) ? f2b(x) : f2b(x - b2f(f2b(x)));
    }
    B1t[i] = o;
    return;
  }
  i -= 737280;
  if (i < 417792) {  // Wgru
    int n = i / 544, k = i - n * 544;
    u16 o = 0;
    if (k < 256) o = f2b(Whh[k * 768 + n]);
    else if (k < 512) { float x = Whh[(k - 256) * 768 + n]; o = f2b(x - b2f(f2b(x))); }
    else if (k < 541) o = f2b(Wih[(260 + k - 512) * 768 + n]);
    Wgru[i] = o;
    return;
  }
  i -= 417792;
  if (i < 8192) {  // Whead
    int n = i / 256, k = i - n * 256;
    u16 o = 0;
    if (n < 16) { if (n < 15) o = f2b(Wt[k * 15 + n]); }
    else { int c = n - 16; if (c < 14) o = f2b(Wp[k * 14 + c]); }
    Whead[i] = o;
    return;
  }
  i -= 8192;
  if (i < 204800) {  // Wedge
    int n = i / 800, k = i - n * 800;
    Wedge[i] = (k < 772) ? f2b(We1[k * 256 + n]) : (u16)0;
    return;
  }
  i -= 204800;
  if (i < 16384) {  // Wn2t
    int n = i / 256, k = i - n * 256;
    Wn2t[i] = (n < 49) ? f2b(Wn2[k * 49 + n]) : (u16)0;
  }
}

// ---------------------------------------------------------------------------
// Generic chunk-mapped split-bf16 GEMM. C[128 x NT] per block.
// Chunk c multiplies A[sel][m, aoff:aoff+32] x Bt[n, boff:boff+32]^T.
// ep: 0 = input fusion (relu1/h0/zcW), 1 = num_nodes out, 2 = edge relu.
// ---------------------------------------------------------------------------
struct CMap { int nc; int asel[44]; int aoff[44]; int boff[44]; };

template <int NT>
__global__ __launch_bounds__(256) void gemm_split(
    const u16* __restrict__ A0, int lda0, const u16* __restrict__ A1, int lda1,
    const u16* __restrict__ Bt, int ldb, CMap cm, int ep,
    const float* __restrict__ pb0, const float* __restrict__ pb1,
    const float* __restrict__ pb2, const float* __restrict__ pb3,
    float* __restrict__ pf0, float* __restrict__ pf1,
    u16* __restrict__ pu0, float* __restrict__ pOut) {
  __shared__ u16 Al[128 * 32];
  __shared__ u16 Bl[NT * 32];
  const int tid = threadIdx.x, w = tid >> 6, lane = tid & 63;
  const int m0 = blockIdx.x * 128, n0 = blockIdx.y * NT;
  const int wm = w & 1, wn = w >> 1;
  constexpr int TN = NT / 32;
  f32x4 acc[4][TN];
#pragma unroll
  for (int mt = 0; mt < 4; ++mt)
#pragma unroll
    for (int nt = 0; nt < TN; ++nt) acc[mt][nt] = (f32x4)(0.f);

  for (int c = 0; c < cm.nc; ++c) {
    const u16* Ap = cm.asel[c] ? A1 : A0;
    const int lda = cm.asel[c] ? lda1 : lda0;
    const int ao = cm.aoff[c], bo = cm.boff[c];
    for (int j = w; j < 8; j += 4) {
      const u16* g = Ap + (size_t)(m0 + j * 16 + (lane >> 2)) * lda + ao + (lane & 3) * 8;
      gload_lds16(g, &Al[j * 512]);
    }
    for (int j = w; j < NT / 16; j += 4) {
      const u16* g = Bt + (size_t)(n0 + j * 16 + (lane >> 2)) * ldb + bo + (lane & 3) * 8;
      gload_lds16(g, &Bl[j * 512]);
    }
    __syncthreads();
    bf16x8 af[4], bv[TN];
#pragma unroll
    for (int mt = 0; mt < 4; ++mt)
      af[mt] = *(const bf16x8*)&Al[(wm * 64 + mt * 16 + (lane & 15)) * 32 + (lane >> 4) * 8];
#pragma unroll
    for (int nt = 0; nt < TN; ++nt)
      bv[nt] = *(const bf16x8*)&Bl[(wn * (NT / 2) + nt * 16 + (lane & 15)) * 32 + (lane >> 4) * 8];
#pragma unroll
    for (int mt = 0; mt < 4; ++mt)
#pragma unroll
      for (int nt = 0; nt < TN; ++nt)
        acc[mt][nt] = MFMA16(af[mt], bv[nt], acc[mt][nt]);
    __syncthreads();
  }

#pragma unroll
  for (int mt = 0; mt < 4; ++mt)
#pragma unroll
    for (int nt = 0; nt < TN; ++nt)
#pragma unroll
      for (int r = 0; r < 4; ++r) {
        int brow = m0 + wm * 64 + mt * 16 + (lane >> 4) * 4 + r;
        int c = n0 + wn * (NT / 2) + nt * 16 + (lane & 15);
        float v = acc[mt][nt][r];
        if (ep == 0) {
          if (c < 256) {
            v = fmaxf(v + pb0[c], 0.f);
            pu0[(size_t)brow * 256 + c] = f2b(v);
          } else if (c < 512) {
            pf0[(size_t)brow * 256 + (c - 256)] = v + pb1[c - 256];
          } else {
            int g = c - 512;
            float b = pb2[g] + (g < 512 ? pb3[g] : 0.f);
            pf1[(size_t)brow * 768 + g] = v + b;
          }
        } else if (ep == 1) {
          if (c < 49) pOut[(size_t)brow * 49 + c] = v + pb0[c];
        } else {
          v = fmaxf(v + pb0[c], 0.f);
          pu0[(size_t)brow * 256 + c] = f2b(v);
        }
      }
}

// ---------------------------------------------------------------------------
// gru_seq: 50 GRU steps, h resident in LDS (bf16 hi+lo), heads fused.
// 256 blocks x 512 threads; block owns 64 batch rows.
// Wave w owns j-columns [32w, 32w+32): gate n-tiles at j, 256+j, 512+j,
// so r/z/n triplets stay in-register for the nonlinearity.
// K chunks (25): c0-7 h_hi*Whh_hi, c8-15 h_hi*Whh_lo, c16-23 h_lo*Whh_hi,
// c24 feat*Wih_bot (n-gate part kept in a separate acc: torch GRU computes
// n = tanh(i_n + r*h_n) and feat belongs to i_n, not h_n).
// ---------------------------------------------------------------------------
#define LDH 264

__global__ __launch_bounds__(512, 2) void gru_seq(
    const float* __restrict__ h0f, const float* __restrict__ zcW,
    const u16* __restrict__ Wgru, const u16* __restrict__ Whead,
    const float* __restrict__ target, const float* __restrict__ bhh,
    const float* __restrict__ bt, const float* __restrict__ bp,
    float* __restrict__ out, u16* __restrict__ Ah) {
  __shared__ u16 Hhi[64 * LDH];
  __shared__ u16 Hlo[64 * LDH];
  __shared__ u16 Ff[64 * 40];
  __shared__ float BHN[256];
  const int tid = threadIdx.x, w = tid >> 6, lane = tid & 63;
  const int colh = lane & 15, quad = lane >> 4;
  const int b0 = blockIdx.x * 64;

  for (int e = tid; e < 64 * 256; e += 512) {
    int r = e >> 8, k = e & 255;
    float v = h0f[(size_t)(b0 + r) * 256 + k];
    u16 hi = f2b(v);
    Hhi[r * LDH + k] = hi;
    Hlo[r * LDH + k] = f2b(v - b2f(hi));
  }
  if (tid < 256) BHN[tid] = bhh[512 + tid];

  const int mt_h = w >> 1, nt_h = w & 1;
  bf16x8 WB[8];
#pragma unroll
  for (int kc = 0; kc < 8; ++kc)
    WB[kc] = *(const bf16x8*)(Whead + ((nt_h * 16 + colh) * 256 + kc * 32 + quad * 8));
  float btv = 0.f;
  if (nt_h == 0) { if (colh < 15) btv = bt[colh]; }
  else           { if (colh < 14) btv = bp[colh]; }

  for (int t = 0; t < 50; ++t) {
    // stage prev features (teacher forcing: zeros at t=0, else target[:,t-1])
    for (int e = tid; e < 64 * 40; e += 512) {
      int r = e / 40, c = e - r * 40;
      float v = 0.f;
      if (t > 0 && c < 29) v = target[((size_t)(b0 + r) * 50 + (t - 1)) * 29 + c];
      Ff[r * 40 + c] = f2b(v);
    }
    __syncthreads();  // B1: feat ready; prev-step head reads of h done

    f32x4 aR[2][4], aZ[2][4], aN[2][4], aFN[2][4];
#pragma unroll
    for (int jt = 0; jt < 2; ++jt)
#pragma unroll
      for (int mt = 0; mt < 4; ++mt) {
        aR[jt][mt] = (f32x4)(0.f); aZ[jt][mt] = (f32x4)(0.f);
        aN[jt][mt] = (f32x4)(0.f); aFN[jt][mt] = (f32x4)(0.f);
      }

#pragma unroll
    for (int c = 0; c < 25; ++c) {
      const int ak = (c < 8) ? c * 32 : (c < 16 ? (c - 8) * 32 : (c < 24 ? (c - 16) * 32 : 0));
      const int bk = (c < 8) ? c * 32 : (c < 16 ? 256 + (c - 8) * 32 : (c < 24 ? (c - 16) * 32 : 512));
      bf16x8 af[4];
#pragma unroll
      for (int mt = 0; mt < 4; ++mt) {
        if (c < 16)      af[mt] = *(const bf16x8*)&Hhi[(mt * 16 + colh) * LDH + ak + quad * 8];
        else if (c < 24) af[mt] = *(const bf16x8*)&Hlo[(mt * 16 + colh) * LDH + ak + quad * 8];
        else             af[mt] = *(const bf16x8*)&Ff[(mt * 16 + colh) * 40 + quad * 8];
      }
      bf16x8 bfr[6];
#pragma unroll
      for (int g = 0; g < 3; ++g)
#pragma unroll
        for (int jt = 0; jt < 2; ++jt) {
          int nn = g * 256 + w * 32 + jt * 16 + colh;
          bfr[g * 2 + jt] = *(const bf16x8*)(Wgru + ((size_t)nn * 544 + bk + quad * 8));
        }
#pragma unroll
      for (int jt = 0; jt < 2; ++jt)
#pragma unroll
        for (int mt = 0; mt < 4; ++mt) {
          aR[jt][mt] = MFMA16(af[mt], bfr[jt], aR[jt][mt]);
          aZ[jt][mt] = MFMA16(af[mt], bfr[2 + jt], aZ[jt][mt]);
          if (c == 24) aFN[jt][mt] = MFMA16(af[mt], bfr[4 + jt], aFN[jt][mt]);
          else         aN[jt][mt]  = MFMA16(af[mt], bfr[4 + jt], aN[jt][mt]);
        }
    }
    __syncthreads();  // B2: all h reads done -> safe to overwrite h

#pragma unroll
    for (int jt = 0; jt < 2; ++jt) {
      const int j = w * 32 + jt * 16 + colh;
#pragma unroll
      for (int mt = 0; mt < 4; ++mt)
#pragma unroll
        for (int r = 0; r < 4; ++r) {
          int row = mt * 16 + quad * 4 + r;
          size_t gb = (size_t)(b0 + row) * 768;
          float gr  = aR[jt][mt][r] + zcW[gb + j];          // has bih+bhh
          float gz  = aZ[jt][mt][r] + zcW[gb + 256 + j];    // has bih+bhh
          float gin = aFN[jt][mt][r] + zcW[gb + 512 + j];   // i_n (has bih)
          float hn  = aN[jt][mt][r] + BHN[j];               // h_n (has bhh)
          float rr = sigm(gr), zz = sigm(gz);
          float nv = tanhfast(gin + rr * hn);
          float hold = b2f(Hhi[row * LDH + j]) + b2f(Hlo[row * LDH + j]);
          float hnew = (1.f - zz) * nv + zz * hold;
          u16 hi = f2b(hnew);
          Hhi[row * LDH + j] = hi;
          Hlo[row * LDH + j] = f2b(hnew - b2f(hi));
        }
    }
    __syncthreads();  // B3: h_new complete

    // heads: wave (mt_h, nt_h) computes 16 rows x 16 cols, K = h hi + lo
    f32x4 ha = (f32x4)(0.f);
#pragma unroll
    for (int kc = 0; kc < 8; ++kc)
      ha = MFMA16(*(const bf16x8*)&Hhi[(mt_h * 16 + colh) * LDH + kc * 32 + quad * 8], WB[kc], ha);
#pragma unroll
    for (int kc = 0; kc < 8; ++kc)
      ha = MFMA16(*(const bf16x8*)&Hlo[(mt_h * 16 + colh) * LDH + kc * 32 + quad * 8], WB[kc], ha);
#pragma unroll
    for (int r = 0; r < 4; ++r) {
      int row = b0 + mt_h * 16 + quad * 4 + r;
      float v = ha[r] + btv;
      if (nt_h == 0) {
        if (colh < 15) out[R1OFF + ((size_t)row * 50 + t) * 15 + colh] = v;
      } else {
        if (colh < 14) out[R2OFF + ((size_t)row * 50 + t) * 14 + colh] = sigm(v);
      }
    }
    // next B1 protects h against the next epilogue's writes
  }

  __syncthreads();
  for (int e = tid; e < 64 * 256; e += 512) {
    int r = e >> 8, k = e & 255;
    Ah[(size_t)(b0 + r) * 512 + k] = Hhi[r * LDH + k];
    Ah[(size_t)(b0 + r) * 512 + 256 + k] = Hlo[r * LDH + k];
  }
}

// ---------------------------------------------------------------------------
// edge_bcast: e[b] = relu_e[b,:] . We2 + be2 ; broadcast to [B, 2450]
// ---------------------------------------------------------------------------
__global__ __launch_bounds__(256) void edge_bcast(
    const u16* __restrict__ relu_e, const float* __restrict__ We2,
    const float* __restrict__ be2, float* __restrict__ out) {
  int wv = threadIdx.x >> 6, lane = threadIdx.x & 63;
  int b = blockIdx.x * 4 + wv;
  const u16* rp = relu_e + (size_t)b * 256;
  float part = 0.f;
#pragma unroll
  for (int i = 0; i < 4; ++i) {
    int k = lane * 4 + i;
    part += b2f(rp[k]) * We2[k];
  }
  for (int o = 32; o > 0; o >>= 1) part += __shfl_down(part, o);
  float e = __shfl(part, 0) + be2[0];
  float* op = out + R3OFF + (size_t)b * 2450;
  for (int i = lane; i < 2450; i += 64) op[i] = e;
}

// ---------------------------------------------------------------------------
extern "C" void kernel_launch(void* const* d_in, const int* in_sizes, int n_in,
                              void* d_out, int out_size, void* d_ws, size_t ws_size,
                              hipStream_t stream) {
  const float* z    = (const float*)d_in[0];
  const float* cond = (const float*)d_in[1];
  const float* tgt  = (const float*)d_in[2];
  const float* Wn1  = (const float*)d_in[3];
  const float* bn1  = (const float*)d_in[4];
  const float* Wn2  = (const float*)d_in[5];
  const float* bn2  = (const float*)d_in[6];
  const float* Wi   = (const float*)d_in[7];
  const float* bi   = (const float*)d_in[8];
  const float* Wih  = (const float*)d_in[9];
  const float* Whh  = (const float*)d_in[10];
  const float* bih  = (const float*)d_in[11];
  const float* bhh  = (const float*)d_in[12];
  const float* Wt   = (const float*)d_in[13];
  const float* bt   = (const float*)d_in[14];
  const float* Wp   = (const float*)d_in[15];
  const float* bp   = (const float*)d_in[16];
  const float* We1  = (const float*)d_in[17];
  const float* be1  = (const float*)d_in[18];
  const float* We2  = (const float*)d_in[19];
  const float* be2  = (const float*)d_in[20];
  float* out = (float*)d_out;
  char* ws = (char*)d_ws;

  // ws layout (bytes)
  u16*   Azc   = (u16*)(ws + 0);                  // 16384x576
  u16*   B1t   = (u16*)(ws + 18874368);           // 1280x576
  u16*   Wgru  = (u16*)(ws + 20348928);           // 768x544
  u16*   Whead = (u16*)(ws + 21184512);           // 32x256
  u16*   Wedge = (u16*)(ws + 21200896);           // 256x800
  u16*   Wn2t  = (u16*)(ws + 21610496);           // 64x256
  u16*   relu1 = (u16*)(ws + 21643264);           // 16384x256 (reused as relu_e)
  float* h0ws  = (float*)(ws + 30031872);         // 16384x256
  float* zcWws = (float*)(ws + 46809088);         // 16384x768
  u16*   Ahws  = (u16*)(ws + 97140736);           // 16384x512
  (void)ws_size; (void)in_sizes; (void)n_in; (void)out_size;

  prep<<<42272, 256, 0, stream>>>(z, cond, Wn1, Wi, Wih, Whh, Wt, Wp, We1, Wn2,
                                  Azc, B1t, Wgru, Whead, Wedge, Wn2t);

  // fused input GEMM: [B,260(zc)] x [Wn1|Wi|Wih_top] -> relu1 / h0 / zcW
  CMap m1; m1.nc = 27;
  for (int c = 0; c < 9; ++c)  { m1.asel[c] = 0; m1.aoff[c] = 32 * c;            m1.boff[c] = 32 * c; }
  for (int c = 9; c < 18; ++c) { m1.asel[c] = 0; m1.aoff[c] = 288 + 32 * (c - 9); m1.boff[c] = 32 * (c - 9); }
  for (int c = 18; c < 27; ++c){ m1.asel[c] = 0; m1.aoff[c] = 32 * (c - 18);     m1.boff[c] = 288 + 32 * (c - 18); }
  gemm_split<128><<<dim3(128, 10), 256, 0, stream>>>(
      Azc, 576, Azc, 576, B1t, 576, m1, 0,
      bn1, bi, bih, bhh, h0ws, zcWws, relu1, nullptr);

  // num_nodes layer 2: relu1 @ Wn2 + bn2 -> out[0:B*49]
  CMap m2; m2.nc = 8;
  for (int c = 0; c < 8; ++c) { m2.asel[c] = 0; m2.aoff[c] = 32 * c; m2.boff[c] = 32 * c; }
  gemm_split<64><<<dim3(128, 1), 256, 0, stream>>>(
      relu1, 256, relu1, 256, Wn2t, 256, m2, 1,
      bn2, nullptr, nullptr, nullptr, nullptr, nullptr, nullptr, out);

  // recurrence + heads
  gru_seq<<<256, 512, 0, stream>>>(h0ws, zcWws, Wgru, Whead, tgt, bhh, bt, bp, out, Ahws);

  // edge layer 1: [h_hi|h_lo (x2 weight blocks)|zc_hi] @ We1 -> relu_e
  CMap m3; m3.nc = 41;
  for (int c = 0; c < 8; ++c)  { m3.asel[c] = 0; m3.aoff[c] = 32 * c;              m3.boff[c] = 32 * c; }
  for (int c = 8; c < 16; ++c) { m3.asel[c] = 0; m3.aoff[c] = 256 + 32 * (c - 8);  m3.boff[c] = 32 * (c - 8); }
  for (int c = 16; c < 24; ++c){ m3.asel[c] = 0; m3.aoff[c] = 32 * (c - 16);       m3.boff[c] = 256 + 32 * (c - 16); }
  for (int c = 24; c < 32; ++c){ m3.asel[c] = 0; m3.aoff[c] = 256 + 32 * (c - 24); m3.boff[c] = 256 + 32 * (c - 24); }
  for (int c = 32; c < 41; ++c){ m3.asel[c] = 1; m3.aoff[c] = 32 * (c - 32);       m3.boff[c] = 512 + 32 * (c - 32); }
  gemm_split<128><<<dim3(128, 2), 256, 0, stream>>>(
      Ahws, 512, Azc, 576, Wedge, 800, m3, 2,
      be1, nullptr, nullptr, nullptr, nullptr, nullptr, relu1, nullptr);

  // edge layer 2 + broadcast
  edge_bcast<<<4096, 256, 0, stream>>>(relu1, We2, be2, out);
}

// Round 2
// 3368.060 us; speedup vs baseline: 2.1120x; 2.1120x over previous
//
#include <hip/hip_runtime.h>
#include <hip/hip_bf16.h>
#include <stdint.h>

// ---------------------------------------------------------------------------
// GraphDecoder forward, MI355X.  R2: latency-bound gru_seq restructured.
//  - zcW (i_r/i_z packed bf16, i_n fp32) persistent in VGPRs (was 2.5 GB of
//    streaming re-reads that evicted the weights from L2 every step)
//  - h state exact in fp32 registers; LDS holds only the bf16 A-operand copy
//  - weights chunk-major in ws, wave-private 6KB slices DMA'd into LDS
//    double buffers via global_load_lds (no VGPR cost, vmcnt-gated)
//  - split reduced to hi*hi + hi*lo (lo*hi dropped; h_lo<=2^-9)
// ---------------------------------------------------------------------------

typedef unsigned short u16;
typedef __attribute__((ext_vector_type(8))) short bf16x8;
typedef __attribute__((ext_vector_type(4))) float f32x4;

#define MFMA16(A, B, C) __builtin_amdgcn_mfma_f32_16x16x32_bf16((A), (B), (C), 0, 0, 0)

#define BATCH 16384
#define R1OFF 802816      // type_logits  [B,50,15]
#define R2OFF 13090816    // param_preds  [B,50,14]
#define R3OFF 24559616    // edge_logits  [B,2450]

__device__ __forceinline__ u16 f2b(float x) {
  union { float f; unsigned u; } v; v.f = x;
  unsigned r = v.u + 0x7fffu + ((v.u >> 16) & 1u);
  return (u16)(r >> 16);
}
__device__ __forceinline__ float b2f(u16 h) {
  union { unsigned u; float f; } v; v.u = ((unsigned)h) << 16; return v.f;
}
__device__ __forceinline__ float sigm(float x) {
  return __builtin_amdgcn_rcpf(1.f + __expf(-x));
}
__device__ __forceinline__ float tanhfast(float x) {
  return 1.f - 2.f * __builtin_amdgcn_rcpf(1.f + __expf(2.f * x));
}
__device__ __forceinline__ void gload_lds16(const u16* g, u16* l) {
  __builtin_amdgcn_global_load_lds(
      (const __attribute__((address_space(1))) unsigned int*)g,
      (__attribute__((address_space(3))) unsigned int*)l, 16, 0, 0);
}

// ---------------------------------------------------------------------------
// prep: bf16 staging buffers in ws.
//  Azc  [16384][576] : cols 0:260 zc_hi, 288:548 zc_lo, rest 0
//  B1t  [1280][576]  : W^T of [Wn1|Wi|Wih_top], hi at 0:260, lo at 288:548
//  Wst  [17][8][6][16][32] : chunk-major GRU weights.
//      chunk c, wave w, gjt=(g*2+jt), row16, k32 -> n = g*256+w*32+jt*16+row16
//      c 0..7  : Whh_hi  k = c*32 + k32
//      c 8..15 : Whh_lo  k = (c-8)*32 + k32
//      c 16    : Wih_bot k32<29 ? Wih[260+k32] : 0
//  Whead[32][256]    : n 0:15 Wt^T, 16:30 Wp^T (hi only)
//  Wedge[256][800]   : We1^T (hi only), k 772:800 zero
//  Wn2t [64][256]    : Wn2^T, rows 49:64 zero
// ---------------------------------------------------------------------------
__global__ __launch_bounds__(256) void prep(
    const float* __restrict__ z, const float* __restrict__ cond,
    const float* __restrict__ Wn1, const float* __restrict__ Wi,
    const float* __restrict__ Wih, const float* __restrict__ Whh,
    const float* __restrict__ Wt, const float* __restrict__ Wp,
    const float* __restrict__ We1, const float* __restrict__ Wn2,
    u16* __restrict__ Azc, u16* __restrict__ B1t, u16* __restrict__ Wst,
    u16* __restrict__ Whead, u16* __restrict__ Wedge, u16* __restrict__ Wn2t) {
  int i = blockIdx.x * 256 + threadIdx.x;
  if (i < 9437184) {  // Azc
    int b = i / 576, k = i - b * 576;
    int kk = (k < 260) ? k : ((k >= 288 && k < 548) ? k - 288 : -1);
    u16 o = 0;
    if (kk >= 0) {
      float x = (kk < 256) ? z[b * 256 + kk] : cond[b * 4 + (kk - 256)];
      o = (k < 260) ? f2b(x) : f2b(x - b2f(f2b(x)));
    }
    Azc[i] = o;
    return;
  }
  i -= 9437184;
  if (i < 737280) {  // B1t
    int n = i / 576, k = i - n * 576;
    int kk = (k < 260) ? k : ((k >= 288 && k < 548) ? k - 288 : -1);
    u16 o = 0;
    if (kk >= 0) {
      float x = (n < 256) ? Wn1[kk * 256 + n]
                          : (n < 512 ? Wi[kk * 256 + (n - 256)]
                                     : Wih[kk * 768 + (n - 512)]);
      o = (k < 260) ? f2b(x) : f2b(x - b2f(f2b(x)));
    }
    B1t[i] = o;
    return;
  }
  i -= 737280;
  if (i < 417792) {  // Wst chunk-major
    int c  = i / 24576;
    int r0 = i - c * 24576;
    int w  = r0 / 3072;
    int r1 = r0 - w * 3072;
    int gjt = r1 / 512;
    int r2  = r1 - gjt * 512;
    int r16 = r2 >> 5, k = r2 & 31;
    int g = gjt >> 1, jt = gjt & 1;
    int n = g * 256 + w * 32 + jt * 16 + r16;
    u16 o = 0;
    if (c < 8) o = f2b(Whh[(c * 32 + k) * 768 + n]);
    else if (c < 16) { float x = Whh[((c - 8) * 32 + k) * 768 + n]; o = f2b(x - b2f(f2b(x))); }
    else if (k < 29) o = f2b(Wih[(260 + k) * 768 + n]);
    Wst[i] = o;
    return;
  }
  i -= 417792;
  if (i < 8192) {  // Whead
    int n = i / 256, k = i - n * 256;
    u16 o = 0;
    if (n < 16) { if (n < 15) o = f2b(Wt[k * 15 + n]); }
    else { int cc = n - 16; if (cc < 14) o = f2b(Wp[k * 14 + cc]); }
    Whead[i] = o;
    return;
  }
  i -= 8192;
  if (i < 204800) {  // Wedge
    int n = i / 800, k = i - n * 800;
    Wedge[i] = (k < 772) ? f2b(We1[k * 256 + n]) : (u16)0;
    return;
  }
  i -= 204800;
  if (i < 16384) {  // Wn2t
    int n = i / 256, k = i - n * 256;
    Wn2t[i] = (n < 49) ? f2b(Wn2[k * 49 + n]) : (u16)0;
  }
}

// ---------------------------------------------------------------------------
// Generic chunk-mapped split-bf16 GEMM (unchanged from R1).
// ---------------------------------------------------------------------------
struct CMap { int nc; int asel[44]; int aoff[44]; int boff[44]; };

template <int NT>
__global__ __launch_bounds__(256) void gemm_split(
    const u16* __restrict__ A0, int lda0, const u16* __restrict__ A1, int lda1,
    const u16* __restrict__ Bt, int ldb, CMap cm, int ep,
    const float* __restrict__ pb0, const float* __restrict__ pb1,
    const float* __restrict__ pb2, const float* __restrict__ pb3,
    float* __restrict__ pf0, float* __restrict__ pf1,
    u16* __restrict__ pu0, float* __restrict__ pOut) {
  __shared__ u16 Al[128 * 32];
  __shared__ u16 Bl[NT * 32];
  const int tid = threadIdx.x, w = tid >> 6, lane = tid & 63;
  const int m0 = blockIdx.x * 128, n0 = blockIdx.y * NT;
  const int wm = w & 1, wn = w >> 1;
  constexpr int TN = NT / 32;
  f32x4 acc[4][TN];
#pragma unroll
  for (int mt = 0; mt < 4; ++mt)
#pragma unroll
    for (int nt = 0; nt < TN; ++nt) acc[mt][nt] = (f32x4)(0.f);

  for (int c = 0; c < cm.nc; ++c) {
    const u16* Ap = cm.asel[c] ? A1 : A0;
    const int lda = cm.asel[c] ? lda1 : lda0;
    const int ao = cm.aoff[c], bo = cm.boff[c];
    for (int j = w; j < 8; j += 4) {
      const u16* g = Ap + (size_t)(m0 + j * 16 + (lane >> 2)) * lda + ao + (lane & 3) * 8;
      gload_lds16(g, &Al[j * 512]);
    }
    for (int j = w; j < NT / 16; j += 4) {
      const u16* g = Bt + (size_t)(n0 + j * 16 + (lane >> 2)) * ldb + bo + (lane & 3) * 8;
      gload_lds16(g, &Bl[j * 512]);
    }
    __syncthreads();
    bf16x8 af[4], bv[TN];
#pragma unroll
    for (int mt = 0; mt < 4; ++mt)
      af[mt] = *(const bf16x8*)&Al[(wm * 64 + mt * 16 + (lane & 15)) * 32 + (lane >> 4) * 8];
#pragma unroll
    for (int nt = 0; nt < TN; ++nt)
      bv[nt] = *(const bf16x8*)&Bl[(wn * (NT / 2) + nt * 16 + (lane & 15)) * 32 + (lane >> 4) * 8];
#pragma unroll
    for (int mt = 0; mt < 4; ++mt)
#pragma unroll
      for (int nt = 0; nt < TN; ++nt)
        acc[mt][nt] = MFMA16(af[mt], bv[nt], acc[mt][nt]);
    __syncthreads();
  }

#pragma unroll
  for (int mt = 0; mt < 4; ++mt)
#pragma unroll
    for (int nt = 0; nt < TN; ++nt)
#pragma unroll
      for (int r = 0; r < 4; ++r) {
        int brow = m0 + wm * 64 + mt * 16 + (lane >> 4) * 4 + r;
        int c = n0 + wn * (NT / 2) + nt * 16 + (lane & 15);
        float v = acc[mt][nt][r];
        if (ep == 0) {
          if (c < 256) {
            v = fmaxf(v + pb0[c], 0.f);
            pu0[(size_t)brow * 256 + c] = f2b(v);
          } else if (c < 512) {
            pf0[(size_t)brow * 256 + (c - 256)] = v + pb1[c - 256];
          } else {
            int g = c - 512;
            float b = pb2[g] + (g < 512 ? pb3[g] : 0.f);
            pf1[(size_t)brow * 768 + g] = v + b;
          }
        } else if (ep == 1) {
          if (c < 49) pOut[(size_t)brow * 49 + c] = v + pb0[c];
        } else {
          v = fmaxf(v + pb0[c], 0.f);
          pu0[(size_t)brow * 256 + c] = f2b(v);
        }
      }
}

// ---------------------------------------------------------------------------
// gru_seq R2. 256 blocks x 512 threads, 64 rows/block.
// Persistent regs/thread: zrz[32] (i_r|i_z bf16 pair), zn[32] fp32 (i_n),
// hreg[32] fp32 state. LDS: Hhi (bf16 A-copy), Wb dbuf (2x8x6KB, wave-
// private DMA), WheadL, Ff, BHN = 150 KB.
// 17 weight chunks/step: 8 hi + 8 lo + 1 feat; 24 MFMA each per wave.
// ---------------------------------------------------------------------------
#define LDH 264

__global__ __launch_bounds__(512, 2) void gru_seq(
    const float* __restrict__ h0f, const float* __restrict__ zcW,
    const u16* __restrict__ Wst, const u16* __restrict__ WheadG,
    const float* __restrict__ target, const float* __restrict__ bhh,
    const float* __restrict__ bt, const float* __restrict__ bp,
    float* __restrict__ out, u16* __restrict__ Ah) {
  __shared__ u16 Hhi[64 * LDH];        // 33792 B
  __shared__ u16 Wb[2 * 8 * 3072];     // 98304 B
  __shared__ u16 WheadL[32 * 256];     // 16384 B
  __shared__ u16 Ff[64 * 32];          // 4096 B
  __shared__ float BHN[256];           // 1024 B
  const int tid = threadIdx.x, w = tid >> 6, lane = tid & 63;
  const int colh = lane & 15, quad = lane >> 4;
  const int b0 = blockIdx.x * 64;

  // ---- persistent per-thread state ----
  unsigned zrz[2][4][4];
  float zn[2][4][4];
  float hreg[2][4][4];
#pragma unroll
  for (int jt = 0; jt < 2; ++jt)
#pragma unroll
    for (int mt = 0; mt < 4; ++mt)
#pragma unroll
      for (int r = 0; r < 4; ++r) {
        int row = mt * 16 + quad * 4 + r;
        int j = w * 32 + jt * 16 + colh;
        size_t gb = (size_t)(b0 + row) * 768;
        float a = zcW[gb + j], bz = zcW[gb + 256 + j];
        zrz[jt][mt][r] = ((unsigned)f2b(a) << 16) | (unsigned)f2b(bz);
        zn[jt][mt][r] = zcW[gb + 512 + j];
        float h = h0f[(size_t)(b0 + row) * 256 + j];
        hreg[jt][mt][r] = h;
        Hhi[row * LDH + j] = f2b(h);
      }
  for (int e = tid; e < 8192; e += 512) WheadL[e] = WheadG[e];
  if (tid < 256) BHN[tid] = bhh[512 + tid];

  const int mt_h = w >> 1, nt_h = w & 1;

  // ---- prologue: DMA chunk 0 into buffer 0 (wave-private slice) ----
  {
    const u16* gs = Wst + (size_t)w * 3072 + lane * 8;
    u16* ls = &Wb[w * 3072 + lane * 8];
#pragma unroll
    for (int q = 0; q < 6; ++q) gload_lds16(gs + q * 512, ls + q * 512);
  }
  unsigned pb = 0;

  for (int t = 0; t < 50; ++t) {
    // stage prev features (teacher forcing)
    for (int e = tid; e < 2048; e += 512) {
      int r = e >> 5, c = e & 31;
      float v = 0.f;
      if (t > 0 && c < 29)
        v = __builtin_nontemporal_load(&target[((size_t)(b0 + r) * 50 + (t - 1)) * 29 + c]);
      Ff[e] = f2b(v);
    }
    __syncthreads();  // B1: Ff ready, Hhi (prologue/epilogue writes) published

    f32x4 aR[2][4], aZ[2][4], aN[2][4], aFN[2][4];
#pragma unroll
    for (int jt = 0; jt < 2; ++jt)
#pragma unroll
      for (int mt = 0; mt < 4; ++mt) {
        aR[jt][mt] = (f32x4)(0.f); aZ[jt][mt] = (f32x4)(0.f);
        aN[jt][mt] = (f32x4)(0.f); aFN[jt][mt] = (f32x4)(0.f);
      }

#pragma unroll
    for (int c = 0; c < 17; ++c) {
      // gate: chunk-c DMA (issued last iteration) must have landed
      asm volatile("s_waitcnt vmcnt(0)" ::: "memory");
      const u16* wbase = &Wb[pb * 24576 + w * 3072];
      bf16x8 bfr[6];
#pragma unroll
      for (int gj = 0; gj < 6; ++gj)
        bfr[gj] = *(const bf16x8*)&wbase[gj * 512 + colh * 32 + quad * 8];
      // issue DMA for next chunk (c16 prefetches chunk 0 of next step)
      {
        const int cn = (c < 16) ? (c + 1) : 0;
        const u16* gs = Wst + ((size_t)cn * 8 + w) * 3072 + lane * 8;
        u16* ls = &Wb[(pb ^ 1) * 24576 + w * 3072 + lane * 8];
#pragma unroll
        for (int q = 0; q < 6; ++q) gload_lds16(gs + q * 512, ls + q * 512);
      }
      const int ak = (c < 8) ? c * 32 : (c - 8) * 32;  // unused for c==16
#pragma unroll
      for (int mt = 0; mt < 4; ++mt) {
        bf16x8 af = (c < 16)
            ? *(const bf16x8*)&Hhi[(mt * 16 + colh) * LDH + ak + quad * 8]
            : *(const bf16x8*)&Ff[(mt * 16 + colh) * 32 + quad * 8];
#pragma unroll
        for (int jt = 0; jt < 2; ++jt) {
          aR[jt][mt] = MFMA16(af, bfr[0 + jt], aR[jt][mt]);
          aZ[jt][mt] = MFMA16(af, bfr[2 + jt], aZ[jt][mt]);
          if (c == 16) aFN[jt][mt] = MFMA16(af, bfr[4 + jt], aFN[jt][mt]);
          else         aN[jt][mt]  = MFMA16(af, bfr[4 + jt], aN[jt][mt]);
        }
      }
      pb ^= 1;
    }
    __syncthreads();  // B2: all Hhi reads done -> safe to overwrite

#pragma unroll
    for (int jt = 0; jt < 2; ++jt)
#pragma unroll
      for (int mt = 0; mt < 4; ++mt)
#pragma unroll
        for (int r = 0; r < 4; ++r) {
          int row = mt * 16 + quad * 4 + r;
          int j = w * 32 + jt * 16 + colh;
          float gr  = aR[jt][mt][r] + b2f((u16)(zrz[jt][mt][r] >> 16));
          float gz  = aZ[jt][mt][r] + b2f((u16)(zrz[jt][mt][r] & 0xffffu));
          float gin = aFN[jt][mt][r] + zn[jt][mt][r];
          float hn  = aN[jt][mt][r] + BHN[j];
          float rr = sigm(gr), zz = sigm(gz);
          float nv = tanhfast(gin + rr * hn);
          float h = (1.f - zz) * nv + zz * hreg[jt][mt][r];
          hreg[jt][mt][r] = h;
          Hhi[row * LDH + j] = f2b(h);
        }
    __syncthreads();  // B3: h_new published

    // heads: wave (mt_h, nt_h) computes 16 rows x 16 cols, K=256 hi-only
    {
      f32x4 ha = (f32x4)(0.f);
#pragma unroll
      for (int kc = 0; kc < 8; ++kc) {
        bf16x8 a = *(const bf16x8*)&Hhi[(mt_h * 16 + colh) * LDH + kc * 32 + quad * 8];
        bf16x8 b = *(const bf16x8*)&WheadL[(nt_h * 16 + colh) * 256 + kc * 32 + quad * 8];
        ha = MFMA16(a, b, ha);
      }
#pragma unroll
      for (int r = 0; r < 4; ++r) {
        int row = b0 + mt_h * 16 + quad * 4 + r;
        float v = ha[r];
        if (nt_h == 0) {
          if (colh < 15)
            __builtin_nontemporal_store(v + bt[colh],
                &out[R1OFF + ((size_t)row * 50 + t) * 15 + colh]);
        } else {
          if (colh < 14)
            __builtin_nontemporal_store(sigm(v + bp[colh]),
                &out[R2OFF + ((size_t)row * 50 + t) * 14 + colh]);
        }
      }
    }
    // next B1 protects Hhi against next epilogue writes
  }

  // final h (hi/lo) for edge GEMM, from exact fp32 state
#pragma unroll
  for (int jt = 0; jt < 2; ++jt)
#pragma unroll
    for (int mt = 0; mt < 4; ++mt)
#pragma unroll
      for (int r = 0; r < 4; ++r) {
        int row = mt * 16 + quad * 4 + r;
        int j = w * 32 + jt * 16 + colh;
        float h = hreg[jt][mt][r];
        u16 hi = f2b(h);
        Ah[(size_t)(b0 + row) * 512 + j] = hi;
        Ah[(size_t)(b0 + row) * 512 + 256 + j] = f2b(h - b2f(hi));
      }
}

// ---------------------------------------------------------------------------
// edge_bcast: e[b] = relu_e[b,:] . We2 + be2 ; broadcast to [B, 2450]
// ---------------------------------------------------------------------------
__global__ __launch_bounds__(256) void edge_bcast(
    const u16* __restrict__ relu_e, const float* __restrict__ We2,
    const float* __restrict__ be2, float* __restrict__ out) {
  int wv = threadIdx.x >> 6, lane = threadIdx.x & 63;
  int b = blockIdx.x * 4 + wv;
  const u16* rp = relu_e + (size_t)b * 256;
  float part = 0.f;
#pragma unroll
  for (int i = 0; i < 4; ++i) {
    int k = lane * 4 + i;
    part += b2f(rp[k]) * We2[k];
  }
  for (int o = 32; o > 0; o >>= 1) part += __shfl_down(part, o);
  float e = __shfl(part, 0) + be2[0];
  float* op = out + R3OFF + (size_t)b * 2450;
  for (int i = lane; i < 2450; i += 64) __builtin_nontemporal_store(e, &op[i]);
}

// ---------------------------------------------------------------------------
extern "C" void kernel_launch(void* const* d_in, const int* in_sizes, int n_in,
                              void* d_out, int out_size, void* d_ws, size_t ws_size,
                              hipStream_t stream) {
  const float* z    = (const float*)d_in[0];
  const float* cond = (const float*)d_in[1];
  const float* tgt  = (const float*)d_in[2];
  const float* Wn1  = (const float*)d_in[3];
  const float* bn1  = (const float*)d_in[4];
  const float* Wn2  = (const float*)d_in[5];
  const float* bn2  = (const float*)d_in[6];
  const float* Wi   = (const float*)d_in[7];
  const float* bi   = (const float*)d_in[8];
  const float* Wih  = (const float*)d_in[9];
  const float* Whh  = (const float*)d_in[10];
  const float* bih  = (const float*)d_in[11];
  const float* bhh  = (const float*)d_in[12];
  const float* Wt   = (const float*)d_in[13];
  const float* bt   = (const float*)d_in[14];
  const float* Wp   = (const float*)d_in[15];
  const float* bp   = (const float*)d_in[16];
  const float* We1  = (const float*)d_in[17];
  const float* be1  = (const float*)d_in[18];
  const float* We2  = (const float*)d_in[19];
  const float* be2  = (const float*)d_in[20];
  float* out = (float*)d_out;
  char* ws = (char*)d_ws;

  // ws layout (bytes)
  u16*   Azc   = (u16*)(ws + 0);                  // 16384x576
  u16*   B1t   = (u16*)(ws + 18874368);           // 1280x576
  u16*   Wstag = (u16*)(ws + 20348928);           // 17x8x3072 (835584 B)
  u16*   Whead = (u16*)(ws + 21184512);           // 32x256
  u16*   Wedge = (u16*)(ws + 21200896);           // 256x800
  u16*   Wn2t  = (u16*)(ws + 21610496);           // 64x256
  u16*   relu1 = (u16*)(ws + 21643264);           // 16384x256 (reused as relu_e)
  float* h0ws  = (float*)(ws + 30031872);         // 16384x256
  float* zcWws = (float*)(ws + 46809088);         // 16384x768
  u16*   Ahws  = (u16*)(ws + 97140736);           // 16384x512
  (void)ws_size; (void)in_sizes; (void)n_in; (void)out_size;

  prep<<<42272, 256, 0, stream>>>(z, cond, Wn1, Wi, Wih, Whh, Wt, Wp, We1, Wn2,
                                  Azc, B1t, Wstag, Whead, Wedge, Wn2t);

  // fused input GEMM: [B,260(zc)] x [Wn1|Wi|Wih_top] -> relu1 / h0 / zcW
  CMap m1; m1.nc = 27;
  for (int c = 0; c < 9; ++c)  { m1.asel[c] = 0; m1.aoff[c] = 32 * c;            m1.boff[c] = 32 * c; }
  for (int c = 9; c < 18; ++c) { m1.asel[c] = 0; m1.aoff[c] = 288 + 32 * (c - 9); m1.boff[c] = 32 * (c - 9); }
  for (int c = 18; c < 27; ++c){ m1.asel[c] = 0; m1.aoff[c] = 32 * (c - 18);     m1.boff[c] = 288 + 32 * (c - 18); }
  gemm_split<128><<<dim3(128, 10), 256, 0, stream>>>(
      Azc, 576, Azc, 576, B1t, 576, m1, 0,
      bn1, bi, bih, bhh, h0ws, zcWws, relu1, nullptr);

  // num_nodes layer 2: relu1 @ Wn2 + bn2 -> out[0:B*49]
  CMap m2; m2.nc = 8;
  for (int c = 0; c < 8; ++c) { m2.asel[c] = 0; m2.aoff[c] = 32 * c; m2.boff[c] = 32 * c; }
  gemm_split<64><<<dim3(128, 1), 256, 0, stream>>>(
      relu1, 256, relu1, 256, Wn2t, 256, m2, 1,
      bn2, nullptr, nullptr, nullptr, nullptr, nullptr, nullptr, out);

  // recurrence + heads
  gru_seq<<<256, 512, 0, stream>>>(h0ws, zcWws, Wstag, Whead, tgt, bhh, bt, bp, out, Ahws);

  // edge layer 1: [h_hi|h_lo|zc_hi] @ We1 -> relu_e
  CMap m3; m3.nc = 41;
  for (int c = 0; c < 8; ++c)  { m3.asel[c] = 0; m3.aoff[c] = 32 * c;              m3.boff[c] = 32 * c; }
  for (int c = 8; c < 16; ++c) { m3.asel[c] = 0; m3.aoff[c] = 256 + 32 * (c - 8);  m3.boff[c] = 32 * (c - 8); }
  for (int c = 16; c < 24; ++c){ m3.asel[c] = 0; m3.aoff[c] = 32 * (c - 16);       m3.boff[c] = 256 + 32 * (c - 16); }
  for (int c = 24; c < 32; ++c){ m3.asel[c] = 0; m3.aoff[c] = 256 + 32 * (c - 24); m3.boff[c] = 256 + 32 * (c - 24); }
  for (int c = 32; c < 41; ++c){ m3.asel[c] = 1; m3.aoff[c] = 32 * (c - 32);       m3.boff[c] = 512 + 32 * (c - 32); }
  gemm_split<128><<<dim3(128, 2), 256, 0, stream>>>(
      Ahws, 512, Azc, 576, Wedge, 800, m3, 2,
      be1, nullptr, nullptr, nullptr, nullptr, nullptr, relu1, nullptr);

  // edge layer 2 + broadcast
  edge_bcast<<<4096, 256, 0, stream>>>(relu1, We2, be2, out);
}

// Round 3
// 2522.554 us; speedup vs baseline: 2.8199x; 1.3352x over previous
//
#include <hip/hip_runtime.h>
#include <hip/hip_bf16.h>
#include <stdint.h>

// ---------------------------------------------------------------------------
// GraphDecoder forward, MI355X.  R3: gru_seq weight path moved LDS->registers.
//  - R2 post-mortem: LDS-DMA double buffer never pipelined (compiler orders
//    global_load_lds -> ds_read conservatively); latency-bound at 9.8% MFMA.
//  - R3: weights hi-only (9 chunks), wave-private slices loaded straight to
//    VGPRs with rotating prefetch (exact compiler vmcnt tracking), raw
//    lgkm-only barriers (no vmcnt drain), feat chunk first + n-part snapshot
//    to fit the 256-reg/wave cap, features pipelined one step ahead.
// ---------------------------------------------------------------------------

typedef unsigned short u16;
typedef __attribute__((ext_vector_type(8))) short bf16x8;
typedef __attribute__((ext_vector_type(4))) float f32x4;

#define MFMA16(A, B, C) __builtin_amdgcn_mfma_f32_16x16x32_bf16((A), (B), (C), 0, 0, 0)

#define BATCH 16384
#define R1OFF 802816      // type_logits  [B,50,15]
#define R2OFF 13090816    // param_preds  [B,50,14]
#define R3OFF 24559616    // edge_logits  [B,2450]

__device__ __forceinline__ u16 f2b(float x) {
  union { float f; unsigned u; } v; v.f = x;
  unsigned r = v.u + 0x7fffu + ((v.u >> 16) & 1u);
  return (u16)(r >> 16);
}
__device__ __forceinline__ float b2f(u16 h) {
  union { unsigned u; float f; } v; v.u = ((unsigned)h) << 16; return v.f;
}
__device__ __forceinline__ float sigm(float x) {
  return __builtin_amdgcn_rcpf(1.f + __expf(-x));
}
__device__ __forceinline__ float tanhfast(float x) {
  return 1.f - 2.f * __builtin_amdgcn_rcpf(1.f + __expf(2.f * x));
}
__device__ __forceinline__ void gload_lds16(const u16* g, u16* l) {
  __builtin_amdgcn_global_load_lds(
      (const __attribute__((address_space(1))) unsigned int*)g,
      (__attribute__((address_space(3))) unsigned int*)l, 16, 0, 0);
}

// ---------------------------------------------------------------------------
// prep: bf16 staging buffers in ws.
//  Azc  [16384][576] : cols 0:260 zc_hi, 288:548 zc_lo, rest 0
//  B1t  [1280][576]  : W^T of [Wn1|Wi|Wih_top], hi at 0:260, lo at 288:548
//  Wst  [9][8][6][16][32] : chunk-major GRU weights (hi only + feat).
//      chunk c, wave w, gjt=(g*2+jt), row16, k32 -> n = g*256+w*32+jt*16+row16
//      c 0..7 : Whh_hi  k = c*32 + k32
//      c 8    : Wih_bot k32<29 ? Wih[260+k32] : 0
//  Whead[32][256]    : n 0:15 Wt^T, 16:30 Wp^T (hi only)
//  Wedge[256][800]   : We1^T (hi only), k 772:800 zero
//  Wn2t [64][256]    : Wn2^T, rows 49:64 zero
// ---------------------------------------------------------------------------
__global__ __launch_bounds__(256) void prep(
    const float* __restrict__ z, const float* __restrict__ cond,
    const float* __restrict__ Wn1, const float* __restrict__ Wi,
    const float* __restrict__ Wih, const float* __restrict__ Whh,
    const float* __restrict__ Wt, const float* __restrict__ Wp,
    const float* __restrict__ We1, const float* __restrict__ Wn2,
    u16* __restrict__ Azc, u16* __restrict__ B1t, u16* __restrict__ Wst,
    u16* __restrict__ Whead, u16* __restrict__ Wedge, u16* __restrict__ Wn2t) {
  int i = blockIdx.x * 256 + threadIdx.x;
  if (i < 9437184) {  // Azc
    int b = i / 576, k = i - b * 576;
    int kk = (k < 260) ? k : ((k >= 288 && k < 548) ? k - 288 : -1);
    u16 o = 0;
    if (kk >= 0) {
      float x = (kk < 256) ? z[b * 256 + kk] : cond[b * 4 + (kk - 256)];
      o = (k < 260) ? f2b(x) : f2b(x - b2f(f2b(x)));
    }
    Azc[i] = o;
    return;
  }
  i -= 9437184;
  if (i < 737280) {  // B1t
    int n = i / 576, k = i - n * 576;
    int kk = (k < 260) ? k : ((k >= 288 && k < 548) ? k - 288 : -1);
    u16 o = 0;
    if (kk >= 0) {
      float x = (n < 256) ? Wn1[kk * 256 + n]
                          : (n < 512 ? Wi[kk * 256 + (n - 256)]
                                     : Wih[kk * 768 + (n - 512)]);
      o = (k < 260) ? f2b(x) : f2b(x - b2f(f2b(x)));
    }
    B1t[i] = o;
    return;
  }
  i -= 737280;
  if (i < 221184) {  // Wst chunk-major (9 chunks)
    int c  = i / 24576;
    int r0 = i - c * 24576;
    int w  = r0 / 3072;
    int r1 = r0 - w * 3072;
    int gjt = r1 / 512;
    int r2  = r1 - gjt * 512;
    int r16 = r2 >> 5, k = r2 & 31;
    int g = gjt >> 1, jt = gjt & 1;
    int n = g * 256 + w * 32 + jt * 16 + r16;
    u16 o = 0;
    if (c < 8) o = f2b(Whh[(c * 32 + k) * 768 + n]);
    else if (k < 29) o = f2b(Wih[(260 + k) * 768 + n]);
    Wst[i] = o;
    return;
  }
  i -= 221184;
  if (i < 8192) {  // Whead
    int n = i / 256, k = i - n * 256;
    u16 o = 0;
    if (n < 16) { if (n < 15) o = f2b(Wt[k * 15 + n]); }
    else { int cc = n - 16; if (cc < 14) o = f2b(Wp[k * 14 + cc]); }
    Whead[i] = o;
    return;
  }
  i -= 8192;
  if (i < 204800) {  // Wedge
    int n = i / 800, k = i - n * 800;
    Wedge[i] = (k < 772) ? f2b(We1[k * 256 + n]) : (u16)0;
    return;
  }
  i -= 204800;
  if (i < 16384) {  // Wn2t
    int n = i / 256, k = i - n * 256;
    Wn2t[i] = (n < 49) ? f2b(Wn2[k * 49 + n]) : (u16)0;
  }
}

// ---------------------------------------------------------------------------
// Generic chunk-mapped split-bf16 GEMM (unchanged from R2).
// ---------------------------------------------------------------------------
struct CMap { int nc; int asel[44]; int aoff[44]; int boff[44]; };

template <int NT>
__global__ __launch_bounds__(256) void gemm_split(
    const u16* __restrict__ A0, int lda0, const u16* __restrict__ A1, int lda1,
    const u16* __restrict__ Bt, int ldb, CMap cm, int ep,
    const float* __restrict__ pb0, const float* __restrict__ pb1,
    const float* __restrict__ pb2, const float* __restrict__ pb3,
    float* __restrict__ pf0, float* __restrict__ pf1,
    u16* __restrict__ pu0, float* __restrict__ pOut) {
  __shared__ u16 Al[128 * 32];
  __shared__ u16 Bl[NT * 32];
  const int tid = threadIdx.x, w = tid >> 6, lane = tid & 63;
  const int m0 = blockIdx.x * 128, n0 = blockIdx.y * NT;
  const int wm = w & 1, wn = w >> 1;
  constexpr int TN = NT / 32;
  f32x4 acc[4][TN];
#pragma unroll
  for (int mt = 0; mt < 4; ++mt)
#pragma unroll
    for (int nt = 0; nt < TN; ++nt) acc[mt][nt] = (f32x4)(0.f);

  for (int c = 0; c < cm.nc; ++c) {
    const u16* Ap = cm.asel[c] ? A1 : A0;
    const int lda = cm.asel[c] ? lda1 : lda0;
    const int ao = cm.aoff[c], bo = cm.boff[c];
    for (int j = w; j < 8; j += 4) {
      const u16* g = Ap + (size_t)(m0 + j * 16 + (lane >> 2)) * lda + ao + (lane & 3) * 8;
      gload_lds16(g, &Al[j * 512]);
    }
    for (int j = w; j < NT / 16; j += 4) {
      const u16* g = Bt + (size_t)(n0 + j * 16 + (lane >> 2)) * ldb + bo + (lane & 3) * 8;
      gload_lds16(g, &Bl[j * 512]);
    }
    __syncthreads();
    bf16x8 af[4], bv[TN];
#pragma unroll
    for (int mt = 0; mt < 4; ++mt)
      af[mt] = *(const bf16x8*)&Al[(wm * 64 + mt * 16 + (lane & 15)) * 32 + (lane >> 4) * 8];
#pragma unroll
    for (int nt = 0; nt < TN; ++nt)
      bv[nt] = *(const bf16x8*)&Bl[(wn * (NT / 2) + nt * 16 + (lane & 15)) * 32 + (lane >> 4) * 8];
#pragma unroll
    for (int mt = 0; mt < 4; ++mt)
#pragma unroll
      for (int nt = 0; nt < TN; ++nt)
        acc[mt][nt] = MFMA16(af[mt], bv[nt], acc[mt][nt]);
    __syncthreads();
  }

#pragma unroll
  for (int mt = 0; mt < 4; ++mt)
#pragma unroll
    for (int nt = 0; nt < TN; ++nt)
#pragma unroll
      for (int r = 0; r < 4; ++r) {
        int brow = m0 + wm * 64 + mt * 16 + (lane >> 4) * 4 + r;
        int c = n0 + wn * (NT / 2) + nt * 16 + (lane & 15);
        float v = acc[mt][nt][r];
        if (ep == 0) {
          if (c < 256) {
            v = fmaxf(v + pb0[c], 0.f);
            pu0[(size_t)brow * 256 + c] = f2b(v);
          } else if (c < 512) {
            pf0[(size_t)brow * 256 + (c - 256)] = v + pb1[c - 256];
          } else {
            int g = c - 512;
            float b = pb2[g] + (g < 512 ? pb3[g] : 0.f);
            pf1[(size_t)brow * 768 + g] = v + b;
          }
        } else if (ep == 1) {
          if (c < 49) pOut[(size_t)brow * 49 + c] = v + pb0[c];
        } else {
          v = fmaxf(v + pb0[c], 0.f);
          pu0[(size_t)brow * 256 + c] = f2b(v);
        }
      }
}

// ---------------------------------------------------------------------------
// gru_seq R3. 256 blocks x 512 threads, 64 rows/block, 1 block/CU.
// Weights: 9 chunks (feat first, then 8 Whh_hi K-slices), wave-private 6KB
// slices streamed into 6x bf16x8 registers with rotating 1-chunk prefetch.
// Per step per CU: 432 KB from L2 (weights, broadcast across 32 CUs/XCD).
// Barriers are raw lgkm-only (no vmem->LDS hazards remain).
// ---------------------------------------------------------------------------
#define LDH 264

__global__ __launch_bounds__(512, 2) void gru_seq(
    const float* __restrict__ h0f, const float* __restrict__ zcW,
    const u16* __restrict__ Wst, const u16* __restrict__ WheadG,
    const float* __restrict__ target, const float* __restrict__ bhh,
    const float* __restrict__ bt, const float* __restrict__ bp,
    float* __restrict__ out, u16* __restrict__ Ah) {
  __shared__ u16 Hhi[64 * LDH];        // 33792 B
  __shared__ u16 Ff[2][64 * 32];       // 8192 B
  __shared__ u16 WheadL[32 * 256];     // 16384 B
  __shared__ float BHN[256];           // 1024 B
  const int tid = threadIdx.x, w = tid >> 6, lane = tid & 63;
  const int colh = lane & 15, quad = lane >> 4;
  const int b0 = blockIdx.x * 64;

  // ---- persistent per-thread zc-derived state (bf16-packed) ----
  unsigned zrz[2][4][4];   // i_r|i_z (with biases)
  unsigned znp[2][4][2];   // i_n zc-part, r-pairs packed
#pragma unroll
  for (int jt = 0; jt < 2; ++jt)
#pragma unroll
    for (int mt = 0; mt < 4; ++mt) {
      float zn4[4];
#pragma unroll
      for (int r = 0; r < 4; ++r) {
        int row = mt * 16 + quad * 4 + r;
        int j = w * 32 + jt * 16 + colh;
        size_t gb = (size_t)(b0 + row) * 768;
        zrz[jt][mt][r] = ((unsigned)f2b(zcW[gb + j]) << 16) | (unsigned)f2b(zcW[gb + 256 + j]);
        zn4[r] = zcW[gb + 512 + j];
      }
      znp[jt][mt][0] = ((unsigned)f2b(zn4[0]) << 16) | (unsigned)f2b(zn4[1]);
      znp[jt][mt][1] = ((unsigned)f2b(zn4[2]) << 16) | (unsigned)f2b(zn4[3]);
    }
  for (int e = tid; e < 16384; e += 512) {
    int r = e >> 8, k = e & 255;
    Hhi[r * LDH + k] = f2b(h0f[(size_t)(b0 + r) * 256 + k]);
  }
  for (int e = tid; e < 8192; e += 512) WheadL[e] = WheadG[e];
  if (tid < 256) BHN[tid] = bhh[512 + tid];
  for (int e = tid; e < 2048; e += 512) Ff[0][e] = 0;
  __syncthreads();

  const int mt_h = w >> 1, nt_h = w & 1;
  const u16* wbase = Wst + (size_t)w * 3072;
  const int toff = colh * 32 + quad * 8;

  // preload first chunk (order[0] = feat, co=8) into registers
  bf16x8 bcur[6], bnxt[6];
#pragma unroll
  for (int gj = 0; gj < 6; ++gj)
    bcur[gj] = *(const bf16x8*)(wbase + (size_t)8 * 24576 + gj * 512 + toff);

  unsigned fnp[2][4][2];   // feat n-part snapshot (r-pairs packed)
  float fr[4];             // next-step features in flight

  for (int t = 0; t < 50; ++t) {
    asm volatile("s_waitcnt lgkmcnt(0)\n\ts_barrier" ::: "memory");  // B1

    // issue next-step feature loads early (used at end of this body)
#pragma unroll
    for (int k = 0; k < 4; ++k) {
      int e = tid + k * 512;
      int r = e >> 5, c = e & 31;
      fr[k] = (c < 29)
          ? __builtin_nontemporal_load(&target[((size_t)(b0 + r) * 50 + t) * 29 + c])
          : 0.f;
    }

    f32x4 aR[2][4], aZ[2][4], aN[2][4];
#pragma unroll
    for (int jt = 0; jt < 2; ++jt)
#pragma unroll
      for (int mt = 0; mt < 4; ++mt) {
        aR[jt][mt] = (f32x4)(0.f); aZ[jt][mt] = (f32x4)(0.f); aN[jt][mt] = (f32x4)(0.f);
      }

#pragma unroll
    for (int c = 0; c < 9; ++c) {
      const int co = (c == 0) ? 8 : (c - 1);   // compute chunk (feat first)
      const int cn = (c == 8) ? 8 : c;         // prefetch chunk for next iter
#pragma unroll
      for (int gj = 0; gj < 6; ++gj)
        bnxt[gj] = *(const bf16x8*)(wbase + (size_t)cn * 24576 + gj * 512 + toff);
#pragma unroll
      for (int mt = 0; mt < 4; ++mt) {
        bf16x8 af = (co == 8)
            ? *(const bf16x8*)&Ff[t & 1][(mt * 16 + colh) * 32 + quad * 8]
            : *(const bf16x8*)&Hhi[(mt * 16 + colh) * LDH + co * 32 + quad * 8];
#pragma unroll
        for (int jt = 0; jt < 2; ++jt) {
          aR[jt][mt] = MFMA16(af, bcur[0 + jt], aR[jt][mt]);
          aZ[jt][mt] = MFMA16(af, bcur[2 + jt], aZ[jt][mt]);
          aN[jt][mt] = MFMA16(af, bcur[4 + jt], aN[jt][mt]);
        }
      }
      if (c == 0) {  // snapshot feat n-part (belongs to i_n, not h_n), reset aN
#pragma unroll
        for (int jt = 0; jt < 2; ++jt)
#pragma unroll
          for (int mt = 0; mt < 4; ++mt) {
            fnp[jt][mt][0] = ((unsigned)f2b(aN[jt][mt][0]) << 16) | (unsigned)f2b(aN[jt][mt][1]);
            fnp[jt][mt][1] = ((unsigned)f2b(aN[jt][mt][2]) << 16) | (unsigned)f2b(aN[jt][mt][3]);
            aN[jt][mt] = (f32x4)(0.f);
          }
      }
#pragma unroll
      for (int gj = 0; gj < 6; ++gj) bcur[gj] = bnxt[gj];
    }
    asm volatile("s_waitcnt lgkmcnt(0)\n\ts_barrier" ::: "memory");  // B2

    // epilogue: gates + h update (each (row,j) owned by exactly one thread)
#pragma unroll
    for (int jt = 0; jt < 2; ++jt)
#pragma unroll
      for (int mt = 0; mt < 4; ++mt)
#pragma unroll
        for (int r = 0; r < 4; ++r) {
          int row = mt * 16 + quad * 4 + r;
          int j = w * 32 + jt * 16 + colh;
          float gr = aR[jt][mt][r] + b2f((u16)(zrz[jt][mt][r] >> 16));
          float gz = aZ[jt][mt][r] + b2f((u16)(zrz[jt][mt][r] & 0xffffu));
          unsigned fp = fnp[jt][mt][r >> 1];
          unsigned zp = znp[jt][mt][r >> 1];
          u16 fh = (r & 1) ? (u16)(fp & 0xffffu) : (u16)(fp >> 16);
          u16 zh = (r & 1) ? (u16)(zp & 0xffffu) : (u16)(zp >> 16);
          float gin = b2f(fh) + b2f(zh);
          float hn = aN[jt][mt][r] + BHN[j];
          float rr = sigm(gr), zz = sigm(gz);
          float nv = tanhfast(gin + rr * hn);
          float hold = b2f(Hhi[row * LDH + j]);
          float h = (1.f - zz) * nv + zz * hold;
          Hhi[row * LDH + j] = f2b(h);
        }
    asm volatile("s_waitcnt lgkmcnt(0)\n\ts_barrier" ::: "memory");  // B3

    // heads: wave (mt_h, nt_h) computes 16 rows x 16 cols, K=256
    {
      f32x4 ha = (f32x4)(0.f);
#pragma unroll
      for (int kc = 0; kc < 8; ++kc) {
        bf16x8 a = *(const bf16x8*)&Hhi[(mt_h * 16 + colh) * LDH + kc * 32 + quad * 8];
        bf16x8 b = *(const bf16x8*)&WheadL[(nt_h * 16 + colh) * 256 + kc * 32 + quad * 8];
        ha = MFMA16(a, b, ha);
      }
#pragma unroll
      for (int r = 0; r < 4; ++r) {
        int row = b0 + mt_h * 16 + quad * 4 + r;
        float v = ha[r];
        if (nt_h == 0) {
          if (colh < 15)
            __builtin_nontemporal_store(v + bt[colh],
                &out[R1OFF + ((size_t)row * 50 + t) * 15 + colh]);
        } else {
          if (colh < 14)
            __builtin_nontemporal_store(sigm(v + bp[colh]),
                &out[R2OFF + ((size_t)row * 50 + t) * 14 + colh]);
        }
      }
    }

    // stage next-step features (read at chunk 0 of t+1, after B1)
#pragma unroll
    for (int k = 0; k < 4; ++k) Ff[(t + 1) & 1][tid + k * 512] = f2b(fr[k]);
  }

  asm volatile("s_waitcnt lgkmcnt(0)\n\ts_barrier" ::: "memory");
  for (int e = tid; e < 16384; e += 512) {
    int r = e >> 8, k = e & 255;
    Ah[(size_t)(b0 + r) * 256 + k] = Hhi[r * LDH + k];
  }
}

// ---------------------------------------------------------------------------
// edge_bcast: e[b] = relu_e[b,:] . We2 + be2 ; broadcast to [B, 2450]
// ---------------------------------------------------------------------------
__global__ __launch_bounds__(256) void edge_bcast(
    const u16* __restrict__ relu_e, const float* __restrict__ We2,
    const float* __restrict__ be2, float* __restrict__ out) {
  int wv = threadIdx.x >> 6, lane = threadIdx.x & 63;
  int b = blockIdx.x * 4 + wv;
  const u16* rp = relu_e + (size_t)b * 256;
  float part = 0.f;
#pragma unroll
  for (int i = 0; i < 4; ++i) {
    int k = lane * 4 + i;
    part += b2f(rp[k]) * We2[k];
  }
  for (int o = 32; o > 0; o >>= 1) part += __shfl_down(part, o);
  float e = __shfl(part, 0) + be2[0];
  float* op = out + R3OFF + (size_t)b * 2450;
  for (int i = lane; i < 2450; i += 64) __builtin_nontemporal_store(e, &op[i]);
}

// ---------------------------------------------------------------------------
extern "C" void kernel_launch(void* const* d_in, const int* in_sizes, int n_in,
                              void* d_out, int out_size, void* d_ws, size_t ws_size,
                              hipStream_t stream) {
  const float* z    = (const float*)d_in[0];
  const float* cond = (const float*)d_in[1];
  const float* tgt  = (const float*)d_in[2];
  const float* Wn1  = (const float*)d_in[3];
  const float* bn1  = (const float*)d_in[4];
  const float* Wn2  = (const float*)d_in[5];
  const float* bn2  = (const float*)d_in[6];
  const float* Wi   = (const float*)d_in[7];
  const float* bi   = (const float*)d_in[8];
  const float* Wih  = (const float*)d_in[9];
  const float* Whh  = (const float*)d_in[10];
  const float* bih  = (const float*)d_in[11];
  const float* bhh  = (const float*)d_in[12];
  const float* Wt   = (const float*)d_in[13];
  const float* bt   = (const float*)d_in[14];
  const float* Wp   = (const float*)d_in[15];
  const float* bp   = (const float*)d_in[16];
  const float* We1  = (const float*)d_in[17];
  const float* be1  = (const float*)d_in[18];
  const float* We2  = (const float*)d_in[19];
  const float* be2  = (const float*)d_in[20];
  float* out = (float*)d_out;
  char* ws = (char*)d_ws;

  // ws layout (bytes)
  u16*   Azc   = (u16*)(ws + 0);                  // 16384x576
  u16*   B1t   = (u16*)(ws + 18874368);           // 1280x576
  u16*   Wstag = (u16*)(ws + 20348928);           // 9x8x3072 (442368 B)
  u16*   Whead = (u16*)(ws + 21184512);           // 32x256
  u16*   Wedge = (u16*)(ws + 21200896);           // 256x800
  u16*   Wn2t  = (u16*)(ws + 21610496);           // 64x256
  u16*   relu1 = (u16*)(ws + 21643264);           // 16384x256 (reused as relu_e)
  float* h0ws  = (float*)(ws + 30031872);         // 16384x256
  float* zcWws = (float*)(ws + 46809088);         // 16384x768
  u16*   Ahws  = (u16*)(ws + 97140736);           // 16384x256 (hi only)
  (void)ws_size; (void)in_sizes; (void)n_in; (void)out_size;

  prep<<<41504, 256, 0, stream>>>(z, cond, Wn1, Wi, Wih, Whh, Wt, Wp, We1, Wn2,
                                  Azc, B1t, Wstag, Whead, Wedge, Wn2t);

  // fused input GEMM: [B,260(zc)] x [Wn1|Wi|Wih_top] -> relu1 / h0 / zcW
  CMap m1; m1.nc = 27;
  for (int c = 0; c < 9; ++c)  { m1.asel[c] = 0; m1.aoff[c] = 32 * c;            m1.boff[c] = 32 * c; }
  for (int c = 9; c < 18; ++c) { m1.asel[c] = 0; m1.aoff[c] = 288 + 32 * (c - 9); m1.boff[c] = 32 * (c - 9); }
  for (int c = 18; c < 27; ++c){ m1.asel[c] = 0; m1.aoff[c] = 32 * (c - 18);     m1.boff[c] = 288 + 32 * (c - 18); }
  gemm_split<128><<<dim3(128, 10), 256, 0, stream>>>(
      Azc, 576, Azc, 576, B1t, 576, m1, 0,
      bn1, bi, bih, bhh, h0ws, zcWws, relu1, nullptr);

  // num_nodes layer 2: relu1 @ Wn2 + bn2 -> out[0:B*49]
  CMap m2; m2.nc = 8;
  for (int c = 0; c < 8; ++c) { m2.asel[c] = 0; m2.aoff[c] = 32 * c; m2.boff[c] = 32 * c; }
  gemm_split<64><<<dim3(128, 1), 256, 0, stream>>>(
      relu1, 256, relu1, 256, Wn2t, 256, m2, 1,
      bn2, nullptr, nullptr, nullptr, nullptr, nullptr, nullptr, out);

  // recurrence + heads
  gru_seq<<<256, 512, 0, stream>>>(h0ws, zcWws, Wstag, Whead, tgt, bhh, bt, bp, out, Ahws);

  // edge layer 1: [h_hi (x2 weight blocks) | zc_hi] @ We1 -> relu_e
  CMap m3; m3.nc = 25;
  for (int c = 0; c < 8; ++c)  { m3.asel[c] = 0; m3.aoff[c] = 32 * c;             m3.boff[c] = 32 * c; }
  for (int c = 8; c < 16; ++c) { m3.asel[c] = 0; m3.aoff[c] = 32 * (c - 8);       m3.boff[c] = 256 + 32 * (c - 8); }
  for (int c = 16; c < 25; ++c){ m3.asel[c] = 1; m3.aoff[c] = 32 * (c - 16);      m3.boff[c] = 512 + 32 * (c - 16); }
  gemm_split<128><<<dim3(128, 2), 256, 0, stream>>>(
      Ahws, 256, Azc, 576, Wedge, 800, m3, 2,
      be1, nullptr, nullptr, nullptr, nullptr, nullptr, relu1, nullptr);

  // edge layer 2 + broadcast
  edge_bcast<<<4096, 256, 0, stream>>>(relu1, We2, be2, out);
}